// Round 4
// baseline (257.840 us; speedup 1.0000x reference)
//
#include <hip/hip_runtime.h>
#include <hip/hip_bf16.h>
#include <stdint.h>

#define NTOK 2048
#define HDIM 1024
#define NEXP 16
#define TOPK 4
#define IR   512
#define ISH  1024
#define RSCALE 2.5f

typedef short bf16x4 __attribute__((ext_vector_type(4)));
typedef short bf16x8 __attribute__((ext_vector_type(8)));
typedef float f32x4  __attribute__((ext_vector_type(4)));

static __device__ __forceinline__ unsigned short f2bf(float f){
  union { float fv; uint32_t u; } v; v.fv = f;
  uint32_t r = v.u + 0x7fffu + ((v.u >> 16) & 1u);
  return (unsigned short)(r >> 16);
}
static __device__ __forceinline__ float bf2f(unsigned short s){
  union { uint32_t u; float f; } v; v.u = ((uint32_t)s) << 16;
  return v.f;
}

static __device__ __forceinline__ void gl_lds16(const void* gp, void* lp){
  __builtin_amdgcn_global_load_lds(
      (const __attribute__((address_space(1))) unsigned int*)gp,
      (__attribute__((address_space(3))) unsigned int*)lp, 16, 0, 0);
}

// ---------- transpose + fp32->bf16 convert: src[R][C] f32 -> dst[C][R] bf16 ----------
__global__ __launch_bounds__(256) void convT_kernel(
    const float* __restrict__ src, unsigned short* __restrict__ dst, int R, int C)
{
  __shared__ float t[64 * 68];
  const int tid = threadIdx.x;
  const size_t bs = (size_t)R * C;
  const float* s = src + blockIdx.z * bs;
  unsigned short* d = dst + blockIdx.z * bs;
  const int c0 = blockIdx.x * 64, r0 = blockIdx.y * 64;
  #pragma unroll
  for (int i = 0; i < 4; i++){
    int r = i * 16 + (tid >> 4);
    int c = (tid & 15) * 4;
    float4 v = *(const float4*)(s + (size_t)(r0 + r) * C + c0 + c);
    *(float4*)(t + r * 68 + c) = v;
  }
  __syncthreads();
  #pragma unroll
  for (int i = 0; i < 4; i++){
    int c = i * 16 + (tid >> 4);
    int r = (tid & 15) * 4;
    bf16x4 pk = { (short)f2bf(t[(r    ) * 68 + c]), (short)f2bf(t[(r + 1) * 68 + c]),
                  (short)f2bf(t[(r + 2) * 68 + c]), (short)f2bf(t[(r + 3) * 68 + c]) };
    *(bf16x4*)(d + (size_t)(c0 + c) * R + r0 + r) = pk;
  }
}

// ---------------- router: logits, sigmoid, top-4, x->bf16 (no atomics) ----------------
__global__ __launch_bounds__(256) void router_kernel(
    const float* __restrict__ x, const float* __restrict__ gw,
    float* __restrict__ topkw, int* __restrict__ choice,
    unsigned short* __restrict__ xbf)
{
  __shared__ float sgw[NEXP][HDIM + 8];
  const int tid = threadIdx.x;
  for (int f = tid; f < HDIM * NEXP; f += 256){
    int i = f >> 4, e = f & 15;
    sgw[e][i] = gw[f];
  }
  __syncthreads();
  const int lane = tid & 63;
  const int t = blockIdx.x * 4 + (tid >> 6);

  float s[NEXP];
  #pragma unroll
  for (int e = 0; e < NEXP; e++) s[e] = 0.f;
  #pragma unroll
  for (int j = 0; j < 8; j++){
    const int off = 128 * j + lane * 2;
    float2 xv = *(const float2*)(x + (size_t)t * HDIM + off);
    ushort2 xs = { f2bf(xv.x), f2bf(xv.y) };
    *(ushort2*)(xbf + (size_t)t * HDIM + off) = xs;
    #pragma unroll
    for (int e = 0; e < NEXP; e++){
      float2 gv = *(const float2*)(&sgw[e][off]);
      s[e] += xv.x * gv.x + xv.y * gv.y;
    }
  }
  #pragma unroll
  for (int e = 0; e < NEXP; e++){
    #pragma unroll
    for (int off = 32; off; off >>= 1)
      s[e] += __shfl_xor(s[e], off);
  }
  float sc[NEXP];
  #pragma unroll
  for (int e = 0; e < NEXP; e++) sc[e] = 1.f / (1.f + __expf(-s[e]));

  unsigned mask = 0; float w[TOPK]; int id[TOPK];
  #pragma unroll
  for (int k = 0; k < TOPK; k++){
    float best = -1e30f; int bi = 0;
    #pragma unroll
    for (int e = 0; e < NEXP; e++){
      if (!((mask >> e) & 1u) && sc[e] > best){ best = sc[e]; bi = e; }
    }
    mask |= 1u << bi; id[k] = bi; w[k] = best;
  }
  float inv = 1.f / (w[0] + w[1] + w[2] + w[3]);
  if (lane == 0){
    #pragma unroll
    for (int k = 0; k < TOPK; k++){
      topkw[t * TOPK + k] = w[k] * inv;
      choice[t * TOPK + k] = id[k];
    }
  }
}

// ---------------- build per-expert lists deterministically ----------------
__global__ __launch_bounds__(256) void build_lists(
    const int* __restrict__ choice, int* __restrict__ counts, int* __restrict__ lists)
{
  const int e = blockIdx.x;
  const int tid = threadIdx.x;
  __shared__ int scnt[256];
  const int base = tid * 32;
  unsigned m = 0; int local = 0;
  #pragma unroll
  for (int i = 0; i < 32; i++){
    bool hit = (choice[base + i] == e);
    m |= (unsigned)hit << i;
    local += hit;
  }
  scnt[tid] = local;
  __syncthreads();
  int v = local;
  for (int off = 1; off < 256; off <<= 1){
    int add = (tid >= off) ? scnt[tid - off] : 0;
    __syncthreads();
    v += add; scnt[tid] = v;
    __syncthreads();
  }
  int pos = v - local;
  #pragma unroll
  for (int i = 0; i < 32; i++){
    if ((m >> i) & 1u) lists[e * NTOK + pos++] = base + i;
  }
  if (tid == 255) counts[e] = v;
}

// ---------------- unified gate_up GEMM + SiLU*mul over 18 experts ----------------
// e<16: routed expert, rows = lists[e]; e=16+j: shared pseudo-expert j (all tokens).
// act row layout: token t, slot s(0..5): act + t*3072 + s*512. Routed slot = aid&3; pseudo slot = 4+j.
__global__ __launch_bounds__(256) void gu_gemm(
    const unsigned short* __restrict__ xbf, const unsigned short* __restrict__ wgu_t,
    const unsigned short* __restrict__ sgu_t, unsigned short* __restrict__ act,
    const int* __restrict__ lists, const int* __restrict__ counts)
{
  constexpr int K = HDIM;
  __shared__ unsigned short sA[128 * 32];
  __shared__ unsigned short sB[128 * 32];
  __shared__ int sAid[128];

  const int tid = threadIdx.x;
  const int e  = blockIdx.z;
  const int n0 = blockIdx.y * 64;
  const bool routed = (e < NEXP);
  const int count = routed ? counts[e] : NTOK;

  const unsigned short* gate_base;
  const unsigned short* up_base;
  if (routed){
    gate_base = wgu_t + (size_t)e * (2 * IR) * K;
    up_base   = gate_base + (size_t)IR * K;
  } else {
    int j = e - NEXP;
    gate_base = sgu_t + (size_t)(j * 512) * K;
    up_base   = sgu_t + (size_t)(ISH + j * 512) * K;
  }

  const int wv = tid >> 6, lane = tid & 63, lr = lane & 15, g = lane >> 4;
  const int wm = wv >> 1, wn = wv & 1;

  const unsigned short* bsrc[2];
  #pragma unroll
  for (int it = 0; it < 2; it++){
    int q = tid + it * 256;
    int c = q >> 2, ko = (q & 3) * 8;
    int grp = c >> 5, within = c & 31;
    int col = n0 + (grp >> 1) * 32 + within;
    bsrc[it] = ((grp & 1) ? up_base : gate_base) + (size_t)col * K + ko;
  }

  for (int mt = blockIdx.x; mt * 128 < count; mt += 16){
    const int m0 = mt * 128;
    __syncthreads();
    if (tid < 128){
      int aid;
      if (!routed) aid = m0 + tid;
      else { int idx = m0 + tid; aid = (idx < count) ? lists[e * NTOK + idx] : lists[e * NTOK]; }
      sAid[tid] = aid;
    }
    __syncthreads();
    const unsigned short* asrc[2];
    #pragma unroll
    for (int it = 0; it < 2; it++){
      int q = tid + it * 256;
      int r = q >> 2, ko = (q & 3) * 8;
      int aid = sAid[r];
      int tok = routed ? (aid >> 2) : aid;
      asrc[it] = xbf + (size_t)tok * HDIM + ko;
    }

    const f32x4 z4 = {0.f, 0.f, 0.f, 0.f};
    f32x4 acc[4][4];
    #pragma unroll
    for (int i = 0; i < 4; i++)
      #pragma unroll
      for (int j = 0; j < 4; j++) acc[i][j] = z4;

    for (int k0 = 0; k0 < K; k0 += 32){
      #pragma unroll
      for (int it = 0; it < 2; it++){
        gl_lds16(asrc[it] + k0, sA + (tid + it * 256) * 8);
        gl_lds16(bsrc[it] + k0, sB + (tid + it * 256) * 8);
      }
      __syncthreads();
      bf16x8 af[4], bfr[4];
      #pragma unroll
      for (int i = 0; i < 4; i++){
        af[i]  = *(const bf16x8*)(sA + (wm * 64 + i * 16 + lr) * 32 + g * 8);
        bfr[i] = *(const bf16x8*)(sB + (wn * 64 + i * 16 + lr) * 32 + g * 8);
      }
      #pragma unroll
      for (int mi = 0; mi < 4; mi++)
        #pragma unroll
        for (int ni = 0; ni < 4; ni++)
          acc[mi][ni] = __builtin_amdgcn_mfma_f32_16x16x32_bf16(af[mi], bfr[ni], acc[mi][ni], 0, 0, 0);
      __syncthreads();
    }

    const int pslot = 4 + (e - NEXP);
    #pragma unroll
    for (int mi = 0; mi < 4; mi++){
      #pragma unroll
      for (int r = 0; r < 4; r++){
        int row = wm * 64 + mi * 16 + g * 4 + r;
        if (m0 + row >= count) continue;
        int aid = sAid[row];
        size_t arow = routed ? ((size_t)(aid >> 2) * 3072 + (aid & 3) * 512)
                             : ((size_t)aid * 3072 + pslot * 512);
        #pragma unroll
        for (int ni = 0; ni < 2; ni++){
          float gv = acc[mi][ni][r];
          float uv = acc[mi][ni + 2][r];
          float a = gv / (1.f + __expf(-gv)) * uv;
          act[arow + n0 + wn * 32 + ni * 16 + lr] = f2bf(a);
        }
      }
    }
  }
}

// ---------------- down GEMM ----------------
// SH: A = act[t*3072 + 2048 .. +1024] (K=1024), B = sdn_t, fp32 store to out.
// !SH: A = act[(aid>>2)*3072 + (aid&3)*512] (K=512), B = wdn_t[e], bf16 store to downout[aid].
template<bool SH>
__global__ __launch_bounds__(256) void down_gemm(
    const unsigned short* __restrict__ act, const unsigned short* __restrict__ wt,
    float* __restrict__ out, unsigned short* __restrict__ downout,
    const int* __restrict__ lists, const int* __restrict__ counts)
{
  constexpr int K = SH ? ISH : IR;
  __shared__ unsigned short sA[128 * 32];
  __shared__ unsigned short sB[128 * 32];
  __shared__ int sAid[128];

  const int tid = threadIdx.x;
  const int e  = SH ? 0 : blockIdx.z;
  const int n0 = blockIdx.y * 128;
  const int count = SH ? NTOK : counts[e];
  const unsigned short* Bt = wt + (SH ? (size_t)0 : (size_t)e * HDIM * IR);

  const int wv = tid >> 6, lane = tid & 63, lr = lane & 15, g = lane >> 4;
  const int wm = wv >> 1, wn = wv & 1;

  const unsigned short* bsrc[2];
  #pragma unroll
  for (int it = 0; it < 2; it++){
    int q = tid + it * 256;
    int c = q >> 2, ko = (q & 3) * 8;
    bsrc[it] = Bt + (size_t)(n0 + c) * K + ko;
  }

  for (int mt = blockIdx.x; mt * 128 < count; mt += 16){
    const int m0 = mt * 128;
    __syncthreads();
    if (tid < 128){
      int aid;
      if (SH) aid = m0 + tid;
      else { int idx = m0 + tid; aid = (idx < count) ? lists[e * NTOK + idx] : lists[e * NTOK]; }
      sAid[tid] = aid;
    }
    __syncthreads();
    const unsigned short* asrc[2];
    #pragma unroll
    for (int it = 0; it < 2; it++){
      int q = tid + it * 256;
      int r = q >> 2, ko = (q & 3) * 8;
      int aid = sAid[r];
      size_t arow = SH ? ((size_t)aid * 3072 + 2048)
                       : ((size_t)(aid >> 2) * 3072 + (aid & 3) * 512);
      asrc[it] = act + arow + ko;
    }

    const f32x4 z4 = {0.f, 0.f, 0.f, 0.f};
    f32x4 acc[4][4];
    #pragma unroll
    for (int i = 0; i < 4; i++)
      #pragma unroll
      for (int j = 0; j < 4; j++) acc[i][j] = z4;

    for (int k0 = 0; k0 < K; k0 += 32){
      #pragma unroll
      for (int it = 0; it < 2; it++){
        gl_lds16(asrc[it] + k0, sA + (tid + it * 256) * 8);
        gl_lds16(bsrc[it] + k0, sB + (tid + it * 256) * 8);
      }
      __syncthreads();
      bf16x8 af[4], bfr[4];
      #pragma unroll
      for (int i = 0; i < 4; i++){
        af[i]  = *(const bf16x8*)(sA + (wm * 64 + i * 16 + lr) * 32 + g * 8);
        bfr[i] = *(const bf16x8*)(sB + (wn * 64 + i * 16 + lr) * 32 + g * 8);
      }
      #pragma unroll
      for (int mi = 0; mi < 4; mi++)
        #pragma unroll
        for (int ni = 0; ni < 4; ni++)
          acc[mi][ni] = __builtin_amdgcn_mfma_f32_16x16x32_bf16(af[mi], bfr[ni], acc[mi][ni], 0, 0, 0);
      __syncthreads();
    }

    #pragma unroll
    for (int mi = 0; mi < 4; mi++){
      #pragma unroll
      for (int r = 0; r < 4; r++){
        int row = wm * 64 + mi * 16 + g * 4 + r;
        if (m0 + row >= count) continue;
        int aid = sAid[row];
        if (SH){
          size_t orow = (size_t)aid * HDIM;
          #pragma unroll
          for (int ni = 0; ni < 4; ni++)
            out[orow + n0 + wn * 64 + ni * 16 + lr] = acc[mi][ni][r];
        } else {
          size_t orow = (size_t)aid * HDIM;
          #pragma unroll
          for (int ni = 0; ni < 4; ni++)
            downout[orow + n0 + wn * 64 + ni * 16 + lr] = f2bf(acc[mi][ni][r]);
        }
      }
    }
  }
}

// ---------------- combine: out += RSCALE * sum_k w_k * down_k ----------------
__global__ __launch_bounds__(256) void combine_kernel(
    float* __restrict__ out, const unsigned short* __restrict__ downout,
    const float* __restrict__ topkw)
{
  const int idx = blockIdx.x * 256 + threadIdx.x;
  const int t = idx >> 8;
  const int c4 = (idx & 255) * 4;
  float4 o = *(float4*)(out + (size_t)t * HDIM + c4);
  float r0 = 0.f, r1 = 0.f, r2 = 0.f, r3 = 0.f;
  #pragma unroll
  for (int k = 0; k < TOPK; k++){
    float w = topkw[t * TOPK + k];
    const ushort4 dv = *(const ushort4*)(downout + (size_t)(t * TOPK + k) * HDIM + c4);
    r0 += w * bf2f(dv.x); r1 += w * bf2f(dv.y);
    r2 += w * bf2f(dv.z); r3 += w * bf2f(dv.w);
  }
  o.x += RSCALE * r0; o.y += RSCALE * r1; o.z += RSCALE * r2; o.w += RSCALE * r3;
  *(float4*)(out + (size_t)t * HDIM + c4) = o;
}

extern "C" void kernel_launch(void* const* d_in, const int* in_sizes, int n_in,
                              void* d_out, int out_size, void* d_ws, size_t ws_size,
                              hipStream_t stream) {
  const float* x   = (const float*)d_in[0];
  const float* gw  = (const float*)d_in[1];
  const float* wgu = (const float*)d_in[2];
  const float* wdn = (const float*)d_in[3];
  const float* sgu = (const float*)d_in[4];
  const float* sdn = (const float*)d_in[5];
  float* out = (float*)d_out;

  char* ws = (char*)d_ws;
  float* topkw = (float*)(ws + 0);                                        // 32 KB
  int* choice  = (int*)(ws + 32768);                                      // 32 KB
  int* counts  = (int*)(ws + 65536);                                      // 256 B
  int* lists   = (int*)(ws + 65792);                                      // 128 KB -> 196864
  unsigned short* xbf   = (unsigned short*)(ws + 197120);                 // 4 MB
  unsigned short* sgu_t = (unsigned short*)(ws + 197120 + 4194304ull);    // 4 MB
  unsigned short* sdn_t = (unsigned short*)(ws + 197120 + 8388608ull);    // 2 MB
  unsigned short* wdn_t = (unsigned short*)(ws + 197120 + 10485760ull);   // 16 MB
  unsigned short* act   = (unsigned short*)(ws + 197120 + 27262976ull);   // 12.58 MB (2048*3072*2)
  unsigned short* wgu_t = (unsigned short*)(ws + 197120 + 39845888ull);   // 32 MB  -> total ~73.6 MB
  // downout (16 MB) aliases wgu_t: wgu_t is dead once gu_gemm completes, and
  // convT rewrites it at the start of every (replayed) launch. Stream-ordered => safe.
  unsigned short* downout = wgu_t;

  router_kernel<<<NTOK / 4, 256, 0, stream>>>(x, gw, topkw, choice, xbf);
  build_lists<<<NEXP, 256, 0, stream>>>(choice, counts, lists);
  convT_kernel<<<dim3(16, 16, NEXP), 256, 0, stream>>>(wgu, wgu_t, HDIM, 2 * IR);
  convT_kernel<<<dim3(16,  8, NEXP), 256, 0, stream>>>(wdn, wdn_t, IR, HDIM);
  convT_kernel<<<dim3(32, 16, 1),    256, 0, stream>>>(sgu, sgu_t, HDIM, 2 * ISH);
  convT_kernel<<<dim3(16, 16, 1),    256, 0, stream>>>(sdn, sdn_t, ISH, HDIM);

  gu_gemm<<<dim3(16, 8, NEXP + 2), 256, 0, stream>>>(xbf, wgu_t, sgu_t, act, lists, counts);
  down_gemm<true ><<<dim3(16, HDIM / 128, 1),    256, 0, stream>>>(act, sdn_t, out, nullptr, nullptr, nullptr);
  down_gemm<false><<<dim3(16, HDIM / 128, NEXP), 256, 0, stream>>>(act, wdn_t, nullptr, downout, lists, counts);
  combine_kernel<<<(NTOK * HDIM / 4) / 256, 256, 0, stream>>>(out, downout, topkw);
}

// Round 5
// 173.311 us; speedup vs baseline: 1.4877x; 1.4877x over previous
//
#include <hip/hip_runtime.h>
#include <hip/hip_bf16.h>
#include <stdint.h>

#define NTOK 2048
#define HDIM 1024
#define NEXP 16
#define TOPK 4
#define IR   512
#define ISH  1024
#define RSCALE 2.5f

typedef short bf16x4 __attribute__((ext_vector_type(4)));
typedef short bf16x8 __attribute__((ext_vector_type(8)));
typedef float f32x4  __attribute__((ext_vector_type(4)));

static __device__ __forceinline__ unsigned short f2bf(float f){
  union { float fv; uint32_t u; } v; v.fv = f;
  uint32_t r = v.u + 0x7fffu + ((v.u >> 16) & 1u);
  return (unsigned short)(r >> 16);
}
static __device__ __forceinline__ float bf2f(unsigned short s){
  union { uint32_t u; float f; } v; v.u = ((uint32_t)s) << 16;
  return v.f;
}

static __device__ __forceinline__ void gl_lds16(const void* gp, void* lp){
  __builtin_amdgcn_global_load_lds(
      (const __attribute__((address_space(1))) unsigned int*)gp,
      (__attribute__((address_space(3))) unsigned int*)lp, 16, 0, 0);
}

// ---------- fused transpose+convert for ALL four weight tensors (one dispatch) ----------
// Each 64x64 tile: src[R][C] f32 -> dst[C][R] bf16.
__global__ __launch_bounds__(256) void convT_all(
    const float* __restrict__ wgu, unsigned short* __restrict__ wgu_t,
    const float* __restrict__ wdn, unsigned short* __restrict__ wdn_t,
    const float* __restrict__ sgu, unsigned short* __restrict__ sgu_t,
    const float* __restrict__ sdn, unsigned short* __restrict__ sdn_t)
{
  __shared__ float t[64 * 68];
  const int tid = threadIdx.x;
  int id = blockIdx.x;
  const float* s; unsigned short* d; int R, C, rt, ct;
  if (id < 4096){                 // wgu: 16 x [1024][1024]
    int e = id >> 8, r = id & 255; rt = r >> 4; ct = r & 15;
    R = 1024; C = 1024; s = wgu + (size_t)e * 1048576; d = wgu_t + (size_t)e * 1048576;
  } else if (id < 6144){          // wdn: 16 x [512][1024]
    id -= 4096; int e = id >> 7, r = id & 127; rt = r >> 4; ct = r & 15;
    R = 512; C = 1024; s = wdn + (size_t)e * 524288; d = wdn_t + (size_t)e * 524288;
  } else if (id < 6656){          // sgu: [1024][2048]
    id -= 6144; rt = id >> 5; ct = id & 31;
    R = 1024; C = 2048; s = sgu; d = sgu_t;
  } else {                        // sdn: [1024][1024]
    id -= 6656; rt = id >> 4; ct = id & 15;
    R = 1024; C = 1024; s = sdn; d = sdn_t;
  }
  const int r0 = rt * 64, c0 = ct * 64;
  #pragma unroll
  for (int i = 0; i < 4; i++){
    int r = i * 16 + (tid >> 4);
    int c = (tid & 15) * 4;
    float4 v = *(const float4*)(s + (size_t)(r0 + r) * C + c0 + c);
    *(float4*)(t + r * 68 + c) = v;
  }
  __syncthreads();
  #pragma unroll
  for (int i = 0; i < 4; i++){
    int c = i * 16 + (tid >> 4);
    int r = (tid & 15) * 4;
    bf16x4 pk = { (short)f2bf(t[(r    ) * 68 + c]), (short)f2bf(t[(r + 1) * 68 + c]),
                  (short)f2bf(t[(r + 2) * 68 + c]), (short)f2bf(t[(r + 3) * 68 + c]) };
    *(bf16x4*)(d + (size_t)(c0 + c) * R + r0 + r) = pk;
  }
}

// ---------------- router: logits, sigmoid, top-4, x->bf16 (no atomics) ----------------
__global__ __launch_bounds__(256) void router_kernel(
    const float* __restrict__ x, const float* __restrict__ gw,
    float* __restrict__ topkw, int* __restrict__ choice,
    unsigned short* __restrict__ xbf)
{
  __shared__ float sgw[NEXP][HDIM + 8];
  const int tid = threadIdx.x;
  for (int f = tid; f < HDIM * NEXP; f += 256){
    int i = f >> 4, e = f & 15;
    sgw[e][i] = gw[f];
  }
  __syncthreads();
  const int lane = tid & 63;
  const int t = blockIdx.x * 4 + (tid >> 6);

  float s[NEXP];
  #pragma unroll
  for (int e = 0; e < NEXP; e++) s[e] = 0.f;
  #pragma unroll
  for (int j = 0; j < 8; j++){
    const int off = 128 * j + lane * 2;
    float2 xv = *(const float2*)(x + (size_t)t * HDIM + off);
    ushort2 xs = { f2bf(xv.x), f2bf(xv.y) };
    *(ushort2*)(xbf + (size_t)t * HDIM + off) = xs;
    #pragma unroll
    for (int e = 0; e < NEXP; e++){
      float2 gv = *(const float2*)(&sgw[e][off]);
      s[e] += xv.x * gv.x + xv.y * gv.y;
    }
  }
  #pragma unroll
  for (int e = 0; e < NEXP; e++){
    #pragma unroll
    for (int off = 32; off; off >>= 1)
      s[e] += __shfl_xor(s[e], off);
  }
  float sc[NEXP];
  #pragma unroll
  for (int e = 0; e < NEXP; e++) sc[e] = 1.f / (1.f + __expf(-s[e]));

  unsigned mask = 0; float w[TOPK]; int id[TOPK];
  #pragma unroll
  for (int k = 0; k < TOPK; k++){
    float best = -1e30f; int bi = 0;
    #pragma unroll
    for (int e = 0; e < NEXP; e++){
      if (!((mask >> e) & 1u) && sc[e] > best){ best = sc[e]; bi = e; }
    }
    mask |= 1u << bi; id[k] = bi; w[k] = best;
  }
  float inv = 1.f / (w[0] + w[1] + w[2] + w[3]);
  if (lane == 0){
    #pragma unroll
    for (int k = 0; k < TOPK; k++){
      topkw[t * TOPK + k] = w[k] * inv;
      choice[t * TOPK + k] = id[k];
    }
  }
}

// ---------------- build per-expert lists deterministically ----------------
__global__ __launch_bounds__(256) void build_lists(
    const int* __restrict__ choice, int* __restrict__ counts, int* __restrict__ lists)
{
  const int e = blockIdx.x;
  const int tid = threadIdx.x;
  __shared__ int scnt[256];
  const int base = tid * 32;
  unsigned m = 0; int local = 0;
  #pragma unroll
  for (int i = 0; i < 32; i++){
    bool hit = (choice[base + i] == e);
    m |= (unsigned)hit << i;
    local += hit;
  }
  scnt[tid] = local;
  __syncthreads();
  int v = local;
  for (int off = 1; off < 256; off <<= 1){
    int add = (tid >= off) ? scnt[tid - off] : 0;
    __syncthreads();
    v += add; scnt[tid] = v;
    __syncthreads();
  }
  int pos = v - local;
  #pragma unroll
  for (int i = 0; i < 32; i++){
    if ((m >> i) & 1u) lists[e * NTOK + pos++] = base + i;
  }
  if (tid == 255) counts[e] = v;
}

// ---------------- fused gate_up GEMM + SiLU*mul (round-3 proven split form) ----------------
template<bool SH>
__global__ __launch_bounds__(256) void gu_gemm(
    const unsigned short* __restrict__ xbf, const unsigned short* __restrict__ wt,
    unsigned short* __restrict__ act,
    const int* __restrict__ lists, const int* __restrict__ counts)
{
  constexpr int NPAIR = SH ? ISH : IR;
  constexpr int K = HDIM;
  constexpr int NCHUNK = SH ? 16 : 4;

  __shared__ unsigned short sA[128 * 32];
  __shared__ unsigned short sB[128 * 32];
  __shared__ int sAid[128];

  const int tid = threadIdx.x;
  const int e  = SH ? 0 : blockIdx.z;
  const int n0 = blockIdx.y * 64;
  const int count = SH ? NTOK : counts[e];
  const unsigned short* Bt = wt + (SH ? (size_t)0 : (size_t)e * (2 * IR) * K);

  const int wv = tid >> 6, lane = tid & 63, lr = lane & 15, g = lane >> 4;
  const int wm = wv >> 1, wn = wv & 1;

  const unsigned short* bsrc[2];
  #pragma unroll
  for (int it = 0; it < 2; it++){
    int q = tid + it * 256;
    int c = q >> 2, ko = (q & 3) * 8;
    int grp = c >> 5, within = c & 31;
    int grow = n0 + (grp >> 1) * 32 + within + ((grp & 1) ? NPAIR : 0);
    bsrc[it] = Bt + (size_t)grow * K + ko;
  }

  for (int mt = blockIdx.x; mt * 128 < count; mt += NCHUNK){
    const int m0 = mt * 128;
    __syncthreads();
    if (tid < 128){
      int aid;
      if (SH) aid = m0 + tid;
      else { int idx = m0 + tid; aid = (idx < count) ? lists[e * NTOK + idx] : lists[e * NTOK]; }
      sAid[tid] = aid;
    }
    __syncthreads();
    const unsigned short* asrc[2];
    #pragma unroll
    for (int it = 0; it < 2; it++){
      int q = tid + it * 256;
      int r = q >> 2, ko = (q & 3) * 8;
      int aid = sAid[r];
      int tok = SH ? aid : (aid >> 2);
      asrc[it] = xbf + (size_t)tok * HDIM + ko;
    }

    const f32x4 z4 = {0.f, 0.f, 0.f, 0.f};
    f32x4 acc[4][4];
    #pragma unroll
    for (int i = 0; i < 4; i++)
      #pragma unroll
      for (int j = 0; j < 4; j++) acc[i][j] = z4;

    for (int k0 = 0; k0 < K; k0 += 32){
      #pragma unroll
      for (int it = 0; it < 2; it++){
        gl_lds16(asrc[it] + k0, sA + (tid + it * 256) * 8);
        gl_lds16(bsrc[it] + k0, sB + (tid + it * 256) * 8);
      }
      __syncthreads();
      bf16x8 af[4], bfr[4];
      #pragma unroll
      for (int i = 0; i < 4; i++){
        af[i]  = *(const bf16x8*)(sA + (wm * 64 + i * 16 + lr) * 32 + g * 8);
        bfr[i] = *(const bf16x8*)(sB + (wn * 64 + i * 16 + lr) * 32 + g * 8);
      }
      #pragma unroll
      for (int mi = 0; mi < 4; mi++)
        #pragma unroll
        for (int ni = 0; ni < 4; ni++)
          acc[mi][ni] = __builtin_amdgcn_mfma_f32_16x16x32_bf16(af[mi], bfr[ni], acc[mi][ni], 0, 0, 0);
      __syncthreads();
    }

    #pragma unroll
    for (int mi = 0; mi < 4; mi++){
      #pragma unroll
      for (int r = 0; r < 4; r++){
        int row = wm * 64 + mi * 16 + g * 4 + r;
        if (!SH && m0 + row >= count) continue;
        int aid = sAid[row];
        size_t arow = (size_t)aid * NPAIR;
        #pragma unroll
        for (int ni = 0; ni < 2; ni++){
          float gv = acc[mi][ni][r];
          float uv = acc[mi][ni + 2][r];
          float a = gv / (1.f + __expf(-gv)) * uv;
          act[arow + n0 + wn * 32 + ni * 16 + lr] = f2bf(a);
        }
      }
    }
  }
}

// ---------------- down GEMM, templated tile-N ----------------
// SH: A = act_s rows (K=1024), fp32 store to out, BNT=64 for 2x block count.
// !SH: A = act_r rows (K=512), bf16 store to downout[aid][HDIM], BNT=128.
template<bool SH, int BNT>
__global__ __launch_bounds__(256) void down_gemm(
    const unsigned short* __restrict__ act, const unsigned short* __restrict__ wt,
    float* __restrict__ out, unsigned short* __restrict__ downout,
    const int* __restrict__ lists, const int* __restrict__ counts)
{
  constexpr int K = SH ? ISH : IR;
  constexpr int NCHUNK = SH ? 16 : 4;
  constexpr int BITER = BNT / 64;         // B-staging iterations (16B x 256 thr = 4KB per iter)
  constexpr int NFR = BNT / 32;           // per-wave N fragments (wn halves the tile)

  __shared__ unsigned short sA[128 * 32];
  __shared__ unsigned short sB[BNT * 32];
  __shared__ int sAid[128];

  const int tid = threadIdx.x;
  const int e  = SH ? 0 : blockIdx.z;
  const int n0 = blockIdx.y * BNT;
  const int count = SH ? NTOK : counts[e];
  const unsigned short* Bt = wt + (SH ? (size_t)0 : (size_t)e * HDIM * IR);

  const int wv = tid >> 6, lane = tid & 63, lr = lane & 15, g = lane >> 4;
  const int wm = wv >> 1, wn = wv & 1;

  const unsigned short* bsrc[BITER];
  #pragma unroll
  for (int it = 0; it < BITER; it++){
    int q = tid + it * 256;
    int c = q >> 2, ko = (q & 3) * 8;
    bsrc[it] = Bt + (size_t)(n0 + c) * K + ko;
  }

  for (int mt = blockIdx.x; mt * 128 < count; mt += NCHUNK){
    const int m0 = mt * 128;
    __syncthreads();
    if (tid < 128){
      int aid;
      if (SH) aid = m0 + tid;
      else { int idx = m0 + tid; aid = (idx < count) ? lists[e * NTOK + idx] : lists[e * NTOK]; }
      sAid[tid] = aid;
    }
    __syncthreads();
    const unsigned short* asrc[2];
    #pragma unroll
    for (int it = 0; it < 2; it++){
      int q = tid + it * 256;
      int r = q >> 2, ko = (q & 3) * 8;
      asrc[it] = act + (size_t)sAid[r] * K + ko;
    }

    const f32x4 z4 = {0.f, 0.f, 0.f, 0.f};
    f32x4 acc[4][NFR];
    #pragma unroll
    for (int i = 0; i < 4; i++)
      #pragma unroll
      for (int j = 0; j < NFR; j++) acc[i][j] = z4;

    for (int k0 = 0; k0 < K; k0 += 32){
      #pragma unroll
      for (int it = 0; it < 2; it++)
        gl_lds16(asrc[it] + k0, sA + (tid + it * 256) * 8);
      #pragma unroll
      for (int it = 0; it < BITER; it++)
        gl_lds16(bsrc[it] + k0, sB + (tid + it * 256) * 8);
      __syncthreads();
      bf16x8 af[4], bfr[NFR];
      #pragma unroll
      for (int i = 0; i < 4; i++)
        af[i]  = *(const bf16x8*)(sA + (wm * 64 + i * 16 + lr) * 32 + g * 8);
      #pragma unroll
      for (int i = 0; i < NFR; i++)
        bfr[i] = *(const bf16x8*)(sB + (wn * (BNT / 2) + i * 16 + lr) * 32 + g * 8);
      #pragma unroll
      for (int mi = 0; mi < 4; mi++)
        #pragma unroll
        for (int ni = 0; ni < NFR; ni++)
          acc[mi][ni] = __builtin_amdgcn_mfma_f32_16x16x32_bf16(af[mi], bfr[ni], acc[mi][ni], 0, 0, 0);
      __syncthreads();
    }

    #pragma unroll
    for (int mi = 0; mi < 4; mi++){
      #pragma unroll
      for (int r = 0; r < 4; r++){
        int row = wm * 64 + mi * 16 + g * 4 + r;
        if (m0 + row >= count) continue;
        int aid = sAid[row];
        if (SH){
          size_t orow = (size_t)aid * HDIM;
          #pragma unroll
          for (int ni = 0; ni < NFR; ni++)
            out[orow + n0 + wn * (BNT / 2) + ni * 16 + lr] = acc[mi][ni][r];
        } else {
          size_t orow = (size_t)aid * HDIM;
          #pragma unroll
          for (int ni = 0; ni < NFR; ni++)
            downout[orow + n0 + wn * (BNT / 2) + ni * 16 + lr] = f2bf(acc[mi][ni][r]);
        }
      }
    }
  }
}

// ---------------- combine: out += RSCALE * sum_k w_k * down_k ----------------
__global__ __launch_bounds__(256) void combine_kernel(
    float* __restrict__ out, const unsigned short* __restrict__ downout,
    const float* __restrict__ topkw)
{
  const int idx = blockIdx.x * 256 + threadIdx.x;
  const int t = idx >> 8;
  const int c4 = (idx & 255) * 4;
  float4 o = *(float4*)(out + (size_t)t * HDIM + c4);
  float r0 = 0.f, r1 = 0.f, r2 = 0.f, r3 = 0.f;
  #pragma unroll
  for (int k = 0; k < TOPK; k++){
    float w = topkw[t * TOPK + k];
    const ushort4 dv = *(const ushort4*)(downout + (size_t)(t * TOPK + k) * HDIM + c4);
    r0 += w * bf2f(dv.x); r1 += w * bf2f(dv.y);
    r2 += w * bf2f(dv.z); r3 += w * bf2f(dv.w);
  }
  o.x += RSCALE * r0; o.y += RSCALE * r1; o.z += RSCALE * r2; o.w += RSCALE * r3;
  *(float4*)(out + (size_t)t * HDIM + c4) = o;
}

extern "C" void kernel_launch(void* const* d_in, const int* in_sizes, int n_in,
                              void* d_out, int out_size, void* d_ws, size_t ws_size,
                              hipStream_t stream) {
  const float* x   = (const float*)d_in[0];
  const float* gw  = (const float*)d_in[1];
  const float* wgu = (const float*)d_in[2];
  const float* wdn = (const float*)d_in[3];
  const float* sgu = (const float*)d_in[4];
  const float* sdn = (const float*)d_in[5];
  float* out = (float*)d_out;

  char* ws = (char*)d_ws;
  float* topkw = (float*)(ws + 0);                                        // 32 KB
  int* choice  = (int*)(ws + 32768);                                      // 32 KB
  int* counts  = (int*)(ws + 65536);                                      // 256 B
  int* lists   = (int*)(ws + 65792);                                      // 128 KB -> 196864
  unsigned short* xbf   = (unsigned short*)(ws + 197120);                 // 4 MB
  unsigned short* wgu_t = (unsigned short*)(ws + 197120 + 4194304ull);    // 32 MB
  unsigned short* wdn_t = (unsigned short*)(ws + 197120 + 37748736ull);   // 16 MB
  unsigned short* sgu_t = (unsigned short*)(ws + 197120 + 54525952ull);   // 4 MB
  unsigned short* sdn_t = (unsigned short*)(ws + 197120 + 58720256ull);   // 2 MB
  unsigned short* act_r = (unsigned short*)(ws + 197120 + 60817408ull);   // 8 MB
  unsigned short* act_s = (unsigned short*)(ws + 197120 + 69206016ull);   // 4 MB -> ~73.6 MB total
  // downout (16 MB) aliases wgu_t: wgu_t's last read is gu_gemm<false>, which completes
  // before down_gemm<false> writes it (same stream); convT_all rewrites it each replay.
  unsigned short* downout = wgu_t;

  router_kernel<<<NTOK / 4, 256, 0, stream>>>(x, gw, topkw, choice, xbf);
  build_lists<<<NEXP, 256, 0, stream>>>(choice, counts, lists);
  convT_all<<<6912, 256, 0, stream>>>(wgu, wgu_t, wdn, wdn_t, sgu, sgu_t, sdn, sdn_t);

  gu_gemm<true ><<<dim3(16, ISH / 64, 1),    256, 0, stream>>>(xbf, sgu_t, act_s, nullptr, nullptr);
  gu_gemm<false><<<dim3(4,  IR  / 64, NEXP), 256, 0, stream>>>(xbf, wgu_t, act_r, lists, counts);
  down_gemm<true , 64><<<dim3(16, HDIM / 64, 1),    256, 0, stream>>>(act_s, sdn_t, out, nullptr, nullptr, nullptr);
  down_gemm<false,128><<<dim3(4,  HDIM / 128, NEXP), 256, 0, stream>>>(act_r, wdn_t, nullptr, downout, lists, counts);
  combine_kernel<<<(NTOK * HDIM / 4) / 256, 256, 0, stream>>>(out, downout, topkw);
}